// Round 1
// baseline (132.935 us; speedup 1.0000x reference)
//
#include <hip/hip_runtime.h>

typedef __bf16 bf16x4 __attribute__((ext_vector_type(4)));
typedef __bf16 bf16x8 __attribute__((ext_vector_type(8)));
typedef float  f32x4v __attribute__((ext_vector_type(4)));

#define HS 136   // padded row stride in bf16 halfwords (272 B, 16B-aligned)

// ---------------------------------------------------------------------------
// inputs fp32, output fp32. h[bn,i,j,f] = Up[bn,i,f]+V[bn,j,f]+delta_ij*Dg[bn,i,f]
//   Up = x_i.W1b + mean.W1e + b1 ; V = x_j.W1c ; Dg = x_i.W1a + mean.W1d
// out = relu(LN_f(h))(+delta_ij*bias_p) @ W2^T + b2
// K1: split-bf16 MFMA (hi/lo, ~fp32-exact) -> Up/V/Dg fp32 ws + W2->bf16.
// K2 (R7): LN + diag + bf16 MFMA GEMM, W2 frags read straight from L2
//          (no LDS staging), swapped MFMA operands -> dwordx4 stores.
// ---------------------------------------------------------------------------

// K1: grid 192 = 32 bn x 6 chunks; chunk ch -> part pidx=ch>>1 (0=Dg,1=Up,2=V),
// f-tiles (4ch..4ch+3)&7 of that part.
__global__ __launch_bounds__(256) void k1_prep(
    const float* __restrict__ x, const float* __restrict__ W1,
    const float* __restrict__ b1, const float* __restrict__ W2,
    float* __restrict__ Up, float* __restrict__ V, float* __restrict__ Dg,
    __bf16* __restrict__ W2b)
{
  __shared__ __align__(16) __bf16 Xhi[64 * HS];
  __shared__ __align__(16) __bf16 Xlo[64 * HS];
  __shared__ float msum[128], pm[256], mw[128];

  const int tid  = threadIdx.x;
  const int bn   = blockIdx.x / 6;
  const int ch   = blockIdx.x % 6;
  const int lane = tid & 63;
  const int w    = tid >> 6;
  const int pidx = ch >> 1;

  if (tid < 128) msum[tid] = 0.f;
  __syncthreads();

  // stage x -> hi/lo bf16 LDS + fp32 column sums (atomic)
  {
    const float4* xv = reinterpret_cast<const float4*>(x + (size_t)bn * 8192);
    const int c = tid & 31;
    float4 ps = {0.f, 0.f, 0.f, 0.f};
#pragma unroll
    for (int it = 0; it < 8; ++it) {
      int p = tid + 256 * it;
      int r = p >> 5;
      float4 v = xv[p];
      ps.x += v.x; ps.y += v.y; ps.z += v.z; ps.w += v.w;
      bf16x4 hv, lv;
      hv[0] = (__bf16)v.x; lv[0] = (__bf16)(v.x - (float)hv[0]);
      hv[1] = (__bf16)v.y; lv[1] = (__bf16)(v.y - (float)hv[1]);
      hv[2] = (__bf16)v.z; lv[2] = (__bf16)(v.z - (float)hv[2]);
      hv[3] = (__bf16)v.w; lv[3] = (__bf16)(v.w - (float)hv[3]);
      *reinterpret_cast<bf16x4*>(&Xhi[r * HS + 4 * c]) = hv;
      *reinterpret_cast<bf16x4*>(&Xlo[r * HS + 4 * c]) = lv;
    }
    atomicAdd(&msum[4 * c + 0], ps.x);
    atomicAdd(&msum[4 * c + 1], ps.y);
    atomicAdd(&msum[4 * c + 2], ps.z);
    atomicAdd(&msum[4 * c + 3], ps.w);
  }

  // W2 fp32 -> bf16 ws (ch==4 blocks, identical writes: benign)
  if (ch == 4) {
    const float4* w2v = reinterpret_cast<const float4*>(W2);
#pragma unroll
    for (int it = 0; it < 16; ++it) {
      int p = tid + 256 * it;
      float4 v = w2v[p];
      bf16x4 hv;
      hv[0] = (__bf16)v.x; hv[1] = (__bf16)v.y;
      hv[2] = (__bf16)v.z; hv[3] = (__bf16)v.w;
      reinterpret_cast<bf16x4*>(W2b)[p] = hv;
    }
  }
  __syncthreads();

  // mean matvec (fp32): 2 threads per f, 64 MACs each; msum holds SUMS (x64)
  {
    const int f  = tid & 127;
    const int hh = tid >> 7;
    float acc = 0.f;
    if (pidx < 2) {
      const float4* wv4 = reinterpret_cast<const float4*>(
          W1 + (size_t)f * 640 + (pidx == 0 ? 384 : 512) + hh * 64);
#pragma unroll
      for (int kc = 0; kc < 16; ++kc) {
        float4 wv = wv4[kc];
        int k = hh * 64 + 4 * kc;
        acc += msum[k] * wv.x + msum[k + 1] * wv.y +
               msum[k + 2] * wv.z + msum[k + 3] * wv.w;
      }
    }
    pm[tid] = acc;
  }
  __syncthreads();
  if (tid < 128)
    mw[tid] = (pm[tid] + pm[tid + 128]) * (1.f / 64.f) +
              (pidx == 1 ? b1[tid] : 0.f);
  __syncthreads();

  // MFMA: wave w owns m-rows 16w..16w+15; 4 f-tiles x 4 ks x 3 (hi/lo) MFMAs
  const int m    = lane & 15;
  const int quad = lane >> 4;
  bf16x8 ahi[4], alo[4];
#pragma unroll
  for (int ks = 0; ks < 4; ++ks) {
    ahi[ks] = *reinterpret_cast<const bf16x8*>(&Xhi[(16 * w + m) * HS + 32 * ks + 8 * quad]);
    alo[ks] = *reinterpret_cast<const bf16x8*>(&Xlo[(16 * w + m) * HS + 32 * ks + 8 * quad]);
  }

  float* rout = (pidx == 0) ? Dg : (pidx == 1 ? Up : V);
#pragma unroll
  for (int tt = 0; tt < 4; ++tt) {
    const int fout = (((4 * ch + tt) & 7) * 16) + m;
    const float* wrow = W1 + (size_t)fout * 640 + pidx * 128;
    f32x4v a = {0.f, 0.f, 0.f, 0.f};
#pragma unroll
    for (int ks = 0; ks < 4; ++ks) {
      float4 w0 = *reinterpret_cast<const float4*>(wrow + 32 * ks + 8 * quad);
      float4 w1 = *reinterpret_cast<const float4*>(wrow + 32 * ks + 8 * quad + 4);
      bf16x8 bhi, blo;
      bhi[0] = (__bf16)w0.x; blo[0] = (__bf16)(w0.x - (float)bhi[0]);
      bhi[1] = (__bf16)w0.y; blo[1] = (__bf16)(w0.y - (float)bhi[1]);
      bhi[2] = (__bf16)w0.z; blo[2] = (__bf16)(w0.z - (float)bhi[2]);
      bhi[3] = (__bf16)w0.w; blo[3] = (__bf16)(w0.w - (float)bhi[3]);
      bhi[4] = (__bf16)w1.x; blo[4] = (__bf16)(w1.x - (float)bhi[4]);
      bhi[5] = (__bf16)w1.y; blo[5] = (__bf16)(w1.y - (float)bhi[5]);
      bhi[6] = (__bf16)w1.z; blo[6] = (__bf16)(w1.z - (float)bhi[6]);
      bhi[7] = (__bf16)w1.w; blo[7] = (__bf16)(w1.w - (float)bhi[7]);
      a = __builtin_amdgcn_mfma_f32_16x16x32_bf16(ahi[ks], bhi, a, 0, 0, 0);
      a = __builtin_amdgcn_mfma_f32_16x16x32_bf16(alo[ks], bhi, a, 0, 0, 0);
      a = __builtin_amdgcn_mfma_f32_16x16x32_bf16(ahi[ks], blo, a, 0, 0, 0);
    }
    const float addv = mw[fout];
#pragma unroll
    for (int rg = 0; rg < 4; ++rg) {
      int ii = 16 * w + 4 * quad + rg;
      rout[((size_t)bn * 64 + ii) * 128 + fout] = a[rg] + addv;
    }
  }
}

// K2 (R7): grid 2048 = (bn, i). LDS only Hs = 17.4 KB -> high occupancy.
// W2 fragments read directly from global (L2-resident, 32 KB reused by all
// 2048 blocks). MFMA operands swapped vs R6: A=W2 rows (d), B=Hs rows (j)
// => D[row=4q+rg -> d, col=m -> j]; rg axis is contiguous d => float4 stores.
__global__ __launch_bounds__(256) void k2_main(
    const float* __restrict__ Up, const float* __restrict__ V,
    const float* __restrict__ Dg, const __bf16* __restrict__ W2b,
    const float* __restrict__ gamma, const float* __restrict__ beta,
    const float* __restrict__ bias_p, const float* __restrict__ b2,
    float* __restrict__ out)
{
  __shared__ __align__(16) __bf16 Hs[64 * HS];

  const int tid  = threadIdx.x;
  const int bid  = blockIdx.x;
  const int bn   = bid >> 6;
  const int i    = bid & 63;
  const int lane = tid & 63;
  const int w    = tid >> 6;

  // h-build + LN; batch the 8 V-row loads first (independent -> MLP)
  {
    const int c    = lane & 31;
    const int half = lane >> 5;
    const size_t base = (size_t)bn * 64;
    const float4 up4 = reinterpret_cast<const float4*>(Up + (base + i) * 128)[c];
    const float4 dg4 = reinterpret_cast<const float4*>(Dg + (base + i) * 128)[c];
    const float4 g4  = reinterpret_cast<const float4*>(gamma)[c];
    const float4 be4 = reinterpret_cast<const float4*>(beta)[c];
    const float4 bp4 = reinterpret_cast<const float4*>(bias_p)[c];
    float4 v4s[8];
#pragma unroll
    for (int it = 0; it < 8; ++it) {
      int r = 8 * it + 2 * w + half;
      v4s[it] = reinterpret_cast<const float4*>(V + (base + r) * 128)[c];
    }
#pragma unroll
    for (int it = 0; it < 8; ++it) {
      int r = 8 * it + 2 * w + half;
      float4 v4 = v4s[it];
      float h0 = v4.x + up4.x, h1 = v4.y + up4.y;
      float h2 = v4.z + up4.z, h3 = v4.w + up4.w;
      if (r == i) { h0 += dg4.x; h1 += dg4.y; h2 += dg4.z; h3 += dg4.w; }
      float s = h0 + h1 + h2 + h3;
      float q = h0 * h0 + h1 * h1 + h2 * h2 + h3 * h3;
#pragma unroll
      for (int off = 16; off > 0; off >>= 1) {
        s += __shfl_xor(s, off, 32);
        q += __shfl_xor(q, off, 32);
      }
      float mu   = s * (1.f / 128.f);
      float var  = q * (1.f / 128.f) - mu * mu;
      float rstd = rsqrtf(var + 1e-5f);
      h0 = fmaxf(fmaf((h0 - mu) * rstd, g4.x, be4.x), 0.f);
      h1 = fmaxf(fmaf((h1 - mu) * rstd, g4.y, be4.y), 0.f);
      h2 = fmaxf(fmaf((h2 - mu) * rstd, g4.z, be4.z), 0.f);
      h3 = fmaxf(fmaf((h3 - mu) * rstd, g4.w, be4.w), 0.f);
      if (r == i) { h0 += bp4.x; h1 += bp4.y; h2 += bp4.z; h3 += bp4.w; }
      bf16x4 hv;
      hv[0] = (__bf16)h0; hv[1] = (__bf16)h1;
      hv[2] = (__bf16)h2; hv[3] = (__bf16)h3;
      *reinterpret_cast<bf16x4*>(&Hs[r * HS + 4 * c]) = hv;
    }
  }
  __syncthreads();

  // MFMA: out(64x128) = Hs x W2^T, operands swapped so d lands on the rg axis.
  // A frag (W2 row d=16t+m, k=32ks+8quad+e) from GLOBAL (L2-hot);
  // B frag (Hs row j=16w+m, same k) from LDS, loaded once.
  const int m    = lane & 15;
  const int quad = lane >> 4;
  bf16x8 bh[4];
#pragma unroll
  for (int ks = 0; ks < 4; ++ks)
    bh[ks] = *reinterpret_cast<const bf16x8*>(
        &Hs[(16 * w + m) * HS + 32 * ks + 8 * quad]);

  const size_t obase = (size_t)bid * 8192;
  const float* orow  = out + obase + (size_t)(16 * w + m) * 128;
#pragma unroll
  for (int t = 0; t < 8; ++t) {
    f32x4v a = {0.f, 0.f, 0.f, 0.f};
#pragma unroll
    for (int ks = 0; ks < 4; ++ks) {
      bf16x8 aw = *reinterpret_cast<const bf16x8*>(
          &W2b[(size_t)(16 * t + m) * 128 + 32 * ks + 8 * quad]);
      a = __builtin_amdgcn_mfma_f32_16x16x32_bf16(aw, bh[ks], a, 0, 0, 0);
    }
    const float4 b2v = *reinterpret_cast<const float4*>(b2 + 16 * t + 4 * quad);
    float4 o;
    o.x = a[0] + b2v.x; o.y = a[1] + b2v.y;
    o.z = a[2] + b2v.z; o.w = a[3] + b2v.w;
    *reinterpret_cast<float4*>(
        const_cast<float*>(orow) + 16 * t + 4 * quad) = o;
  }
}

extern "C" void kernel_launch(void* const* d_in, const int* in_sizes, int n_in,
                              void* d_out, int out_size, void* d_ws, size_t ws_size,
                              hipStream_t stream) {
  const float* x      = (const float*)d_in[0];
  const float* W1     = (const float*)d_in[1];
  const float* b1     = (const float*)d_in[2];
  const float* gamma  = (const float*)d_in[3];
  const float* beta   = (const float*)d_in[4];
  const float* bias_p = (const float*)d_in[5];
  const float* W2     = (const float*)d_in[6];
  const float* b2     = (const float*)d_in[7];

  float*  Up  = (float*)d_ws;
  float*  V   = Up + 2048 * 128;
  float*  Dg  = V + 2048 * 128;
  __bf16* W2b = (__bf16*)(Dg + 2048 * 128);

  k1_prep<<<192, 256, 0, stream>>>(x, W1, b1, W2, Up, V, Dg, W2b);
  k2_main<<<2048, 256, 0, stream>>>(Up, V, Dg, W2b, gamma, beta, bias_p, b2,
                                    (float*)d_out);
}

// Round 2
// 113.739 us; speedup vs baseline: 1.1688x; 1.1688x over previous
//
#include <hip/hip_runtime.h>

typedef __bf16 bf16x4 __attribute__((ext_vector_type(4)));
typedef __bf16 bf16x8 __attribute__((ext_vector_type(8)));
typedef float  f32x4v __attribute__((ext_vector_type(4)));

#define HS 136   // padded row stride in bf16 halfwords (272 B, 16B-aligned)

// ---------------------------------------------------------------------------
// inputs fp32, output fp32. h[bn,i,j,f] = Up[bn,i,f]+V[bn,j,f]+delta_ij*Dg[bn,i,f]
//   Up = x_i.W1b + mean.W1e + b1 ; V = x_j.W1c ; Dg = x_i.W1a + mean.W1d
// out = relu(LN_f(h))(+delta_ij*bias_p) @ W2^T + b2
// K1: split-bf16 MFMA (hi/lo, ~fp32-exact) -> Up/V/Dg fp32 ws + W2->bf16.
// K2 (R8): R6 LDS-staged W2 (L2 hot-spot fix: R7 direct-global regressed
//          52us, latency-bound MfmaUtil 3%) + R7 swapped operands so the
//          rg register axis = innermost d => global_store_dwordx4.
// ---------------------------------------------------------------------------

// K1: grid 192 = 32 bn x 6 chunks; chunk ch -> part pidx=ch>>1 (0=Dg,1=Up,2=V),
// f-tiles (4ch..4ch+3)&7 of that part.
__global__ __launch_bounds__(256) void k1_prep(
    const float* __restrict__ x, const float* __restrict__ W1,
    const float* __restrict__ b1, const float* __restrict__ W2,
    float* __restrict__ Up, float* __restrict__ V, float* __restrict__ Dg,
    __bf16* __restrict__ W2b)
{
  __shared__ __align__(16) __bf16 Xhi[64 * HS];
  __shared__ __align__(16) __bf16 Xlo[64 * HS];
  __shared__ float msum[128], pm[256], mw[128];

  const int tid  = threadIdx.x;
  const int bn   = blockIdx.x / 6;
  const int ch   = blockIdx.x % 6;
  const int lane = tid & 63;
  const int w    = tid >> 6;
  const int pidx = ch >> 1;

  if (tid < 128) msum[tid] = 0.f;
  __syncthreads();

  // stage x -> hi/lo bf16 LDS + fp32 column sums (atomic)
  {
    const float4* xv = reinterpret_cast<const float4*>(x + (size_t)bn * 8192);
    const int c = tid & 31;
    float4 ps = {0.f, 0.f, 0.f, 0.f};
#pragma unroll
    for (int it = 0; it < 8; ++it) {
      int p = tid + 256 * it;
      int r = p >> 5;
      float4 v = xv[p];
      ps.x += v.x; ps.y += v.y; ps.z += v.z; ps.w += v.w;
      bf16x4 hv, lv;
      hv[0] = (__bf16)v.x; lv[0] = (__bf16)(v.x - (float)hv[0]);
      hv[1] = (__bf16)v.y; lv[1] = (__bf16)(v.y - (float)hv[1]);
      hv[2] = (__bf16)v.z; lv[2] = (__bf16)(v.z - (float)hv[2]);
      hv[3] = (__bf16)v.w; lv[3] = (__bf16)(v.w - (float)hv[3]);
      *reinterpret_cast<bf16x4*>(&Xhi[r * HS + 4 * c]) = hv;
      *reinterpret_cast<bf16x4*>(&Xlo[r * HS + 4 * c]) = lv;
    }
    atomicAdd(&msum[4 * c + 0], ps.x);
    atomicAdd(&msum[4 * c + 1], ps.y);
    atomicAdd(&msum[4 * c + 2], ps.z);
    atomicAdd(&msum[4 * c + 3], ps.w);
  }

  // W2 fp32 -> bf16 ws (ch==4 blocks, identical writes: benign)
  if (ch == 4) {
    const float4* w2v = reinterpret_cast<const float4*>(W2);
#pragma unroll
    for (int it = 0; it < 16; ++it) {
      int p = tid + 256 * it;
      float4 v = w2v[p];
      bf16x4 hv;
      hv[0] = (__bf16)v.x; hv[1] = (__bf16)v.y;
      hv[2] = (__bf16)v.z; hv[3] = (__bf16)v.w;
      reinterpret_cast<bf16x4*>(W2b)[p] = hv;
    }
  }
  __syncthreads();

  // mean matvec (fp32): 2 threads per f, 64 MACs each; msum holds SUMS (x64)
  {
    const int f  = tid & 127;
    const int hh = tid >> 7;
    float acc = 0.f;
    if (pidx < 2) {
      const float4* wv4 = reinterpret_cast<const float4*>(
          W1 + (size_t)f * 640 + (pidx == 0 ? 384 : 512) + hh * 64);
#pragma unroll
      for (int kc = 0; kc < 16; ++kc) {
        float4 wv = wv4[kc];
        int k = hh * 64 + 4 * kc;
        acc += msum[k] * wv.x + msum[k + 1] * wv.y +
               msum[k + 2] * wv.z + msum[k + 3] * wv.w;
      }
    }
    pm[tid] = acc;
  }
  __syncthreads();
  if (tid < 128)
    mw[tid] = (pm[tid] + pm[tid + 128]) * (1.f / 64.f) +
              (pidx == 1 ? b1[tid] : 0.f);
  __syncthreads();

  // MFMA: wave w owns m-rows 16w..16w+15; 4 f-tiles x 4 ks x 3 (hi/lo) MFMAs
  const int m    = lane & 15;
  const int quad = lane >> 4;
  bf16x8 ahi[4], alo[4];
#pragma unroll
  for (int ks = 0; ks < 4; ++ks) {
    ahi[ks] = *reinterpret_cast<const bf16x8*>(&Xhi[(16 * w + m) * HS + 32 * ks + 8 * quad]);
    alo[ks] = *reinterpret_cast<const bf16x8*>(&Xlo[(16 * w + m) * HS + 32 * ks + 8 * quad]);
  }

  float* rout = (pidx == 0) ? Dg : (pidx == 1 ? Up : V);
#pragma unroll
  for (int tt = 0; tt < 4; ++tt) {
    const int fout = (((4 * ch + tt) & 7) * 16) + m;
    const float* wrow = W1 + (size_t)fout * 640 + pidx * 128;
    f32x4v a = {0.f, 0.f, 0.f, 0.f};
#pragma unroll
    for (int ks = 0; ks < 4; ++ks) {
      float4 w0 = *reinterpret_cast<const float4*>(wrow + 32 * ks + 8 * quad);
      float4 w1 = *reinterpret_cast<const float4*>(wrow + 32 * ks + 8 * quad + 4);
      bf16x8 bhi, blo;
      bhi[0] = (__bf16)w0.x; blo[0] = (__bf16)(w0.x - (float)bhi[0]);
      bhi[1] = (__bf16)w0.y; blo[1] = (__bf16)(w0.y - (float)bhi[1]);
      bhi[2] = (__bf16)w0.z; blo[2] = (__bf16)(w0.z - (float)bhi[2]);
      bhi[3] = (__bf16)w0.w; blo[3] = (__bf16)(w0.w - (float)bhi[3]);
      bhi[4] = (__bf16)w1.x; blo[4] = (__bf16)(w1.x - (float)bhi[4]);
      bhi[5] = (__bf16)w1.y; blo[5] = (__bf16)(w1.y - (float)bhi[5]);
      bhi[6] = (__bf16)w1.z; blo[6] = (__bf16)(w1.z - (float)bhi[6]);
      bhi[7] = (__bf16)w1.w; blo[7] = (__bf16)(w1.w - (float)bhi[7]);
      a = __builtin_amdgcn_mfma_f32_16x16x32_bf16(ahi[ks], bhi, a, 0, 0, 0);
      a = __builtin_amdgcn_mfma_f32_16x16x32_bf16(alo[ks], bhi, a, 0, 0, 0);
      a = __builtin_amdgcn_mfma_f32_16x16x32_bf16(ahi[ks], blo, a, 0, 0, 0);
    }
    const float addv = mw[fout];
#pragma unroll
    for (int rg = 0; rg < 4; ++rg) {
      int ii = 16 * w + 4 * quad + rg;
      rout[((size_t)bn * 64 + ii) * 128 + fout] = a[rg] + addv;
    }
  }
}

// K2 (R8): grid 2048 = (bn, i). LDS 52.2 KB -> 3 blocks/CU.
// W2 staged in LDS (streamed copy, latency hidden under h-build).
// MFMA operands: A = W2s row (d), B = Hs row (j)
//   => D[row=4*quad+rg -> d, col=m -> j]; rg contiguous in d => float4 stores.
__global__ __launch_bounds__(256) void k2_main(
    const float* __restrict__ Up, const float* __restrict__ V,
    const float* __restrict__ Dg, const __bf16* __restrict__ W2b,
    const float* __restrict__ gamma, const float* __restrict__ beta,
    const float* __restrict__ bias_p, const float* __restrict__ b2,
    float* __restrict__ out)
{
  __shared__ __align__(16) __bf16 W2s[128 * HS];
  __shared__ __align__(16) __bf16 Hs[64 * HS];

  const int tid  = threadIdx.x;
  const int bid  = blockIdx.x;
  const int bn   = bid >> 6;
  const int i    = bid & 63;
  const int lane = tid & 63;
  const int w    = tid >> 6;

  // stage W2 bf16 into padded LDS (one streamed 32 KB copy per block;
  // latency hides under the h-build phase below)
  {
    const uint4* w2v = reinterpret_cast<const uint4*>(W2b);
#pragma unroll
    for (int it = 0; it < 8; ++it) {
      int p   = tid + 256 * it;
      int row = p >> 4;
      int col = (p & 15) * 8;
      *reinterpret_cast<uint4*>(&W2s[row * HS + col]) = w2v[p];
    }
  }

  // h-build + LN; batch the 8 V-row loads first (independent -> MLP)
  {
    const int c    = lane & 31;
    const int half = lane >> 5;
    const size_t base = (size_t)bn * 64;
    const float4 up4 = reinterpret_cast<const float4*>(Up + (base + i) * 128)[c];
    const float4 dg4 = reinterpret_cast<const float4*>(Dg + (base + i) * 128)[c];
    const float4 g4  = reinterpret_cast<const float4*>(gamma)[c];
    const float4 be4 = reinterpret_cast<const float4*>(beta)[c];
    const float4 bp4 = reinterpret_cast<const float4*>(bias_p)[c];
    float4 v4s[8];
#pragma unroll
    for (int it = 0; it < 8; ++it) {
      int r = 8 * it + 2 * w + half;
      v4s[it] = reinterpret_cast<const float4*>(V + (base + r) * 128)[c];
    }
#pragma unroll
    for (int it = 0; it < 8; ++it) {
      int r = 8 * it + 2 * w + half;
      float4 v4 = v4s[it];
      float h0 = v4.x + up4.x, h1 = v4.y + up4.y;
      float h2 = v4.z + up4.z, h3 = v4.w + up4.w;
      if (r == i) { h0 += dg4.x; h1 += dg4.y; h2 += dg4.z; h3 += dg4.w; }
      float s = h0 + h1 + h2 + h3;
      float q = h0 * h0 + h1 * h1 + h2 * h2 + h3 * h3;
#pragma unroll
      for (int off = 16; off > 0; off >>= 1) {
        s += __shfl_xor(s, off, 32);
        q += __shfl_xor(q, off, 32);
      }
      float mu   = s * (1.f / 128.f);
      float var  = q * (1.f / 128.f) - mu * mu;
      float rstd = rsqrtf(var + 1e-5f);
      h0 = fmaxf(fmaf((h0 - mu) * rstd, g4.x, be4.x), 0.f);
      h1 = fmaxf(fmaf((h1 - mu) * rstd, g4.y, be4.y), 0.f);
      h2 = fmaxf(fmaf((h2 - mu) * rstd, g4.z, be4.z), 0.f);
      h3 = fmaxf(fmaf((h3 - mu) * rstd, g4.w, be4.w), 0.f);
      if (r == i) { h0 += bp4.x; h1 += bp4.y; h2 += bp4.z; h3 += bp4.w; }
      bf16x4 hv;
      hv[0] = (__bf16)h0; hv[1] = (__bf16)h1;
      hv[2] = (__bf16)h2; hv[3] = (__bf16)h3;
      *reinterpret_cast<bf16x4*>(&Hs[r * HS + 4 * c]) = hv;
    }
  }
  __syncthreads();

  // MFMA: out(64x128) = Hs x W2^T, operands swapped so d lands on the rg axis.
  // A frag: W2s row d=16t+m, k=32ks+8quad+e (LDS)
  // B frag: Hs  row j=16w+m, same k (LDS, loaded once)
  const int m    = lane & 15;
  const int quad = lane >> 4;
  bf16x8 bh[4];
#pragma unroll
  for (int ks = 0; ks < 4; ++ks)
    bh[ks] = *reinterpret_cast<const bf16x8*>(
        &Hs[(16 * w + m) * HS + 32 * ks + 8 * quad]);

  const size_t obase = (size_t)bid * 8192;
  float* orow = out + obase + (size_t)(16 * w + m) * 128;
#pragma unroll
  for (int t = 0; t < 8; ++t) {
    f32x4v a = {0.f, 0.f, 0.f, 0.f};
#pragma unroll
    for (int ks = 0; ks < 4; ++ks) {
      bf16x8 aw = *reinterpret_cast<const bf16x8*>(
          &W2s[(16 * t + m) * HS + 32 * ks + 8 * quad]);
      a = __builtin_amdgcn_mfma_f32_16x16x32_bf16(aw, bh[ks], a, 0, 0, 0);
    }
    const float4 b2v = *reinterpret_cast<const float4*>(b2 + 16 * t + 4 * quad);
    float4 o;
    o.x = a[0] + b2v.x; o.y = a[1] + b2v.y;
    o.z = a[2] + b2v.z; o.w = a[3] + b2v.w;
    *reinterpret_cast<float4*>(orow + 16 * t + 4 * quad) = o;
  }
}

extern "C" void kernel_launch(void* const* d_in, const int* in_sizes, int n_in,
                              void* d_out, int out_size, void* d_ws, size_t ws_size,
                              hipStream_t stream) {
  const float* x      = (const float*)d_in[0];
  const float* W1     = (const float*)d_in[1];
  const float* b1     = (const float*)d_in[2];
  const float* gamma  = (const float*)d_in[3];
  const float* beta   = (const float*)d_in[4];
  const float* bias_p = (const float*)d_in[5];
  const float* W2     = (const float*)d_in[6];
  const float* b2     = (const float*)d_in[7];

  float*  Up  = (float*)d_ws;
  float*  V   = Up + 2048 * 128;
  float*  Dg  = V + 2048 * 128;
  __bf16* W2b = (__bf16*)(Dg + 2048 * 128);

  k1_prep<<<192, 256, 0, stream>>>(x, W1, b1, W2, Up, V, Dg, W2b);
  k2_main<<<2048, 256, 0, stream>>>(Up, V, Dg, W2b, gamma, beta, bias_p, b2,
                                    (float*)d_out);
}